// Round 2
// baseline (942.486 us; speedup 1.0000x reference)
//
#include <hip/hip_runtime.h>
#include <math.h>

#define N_NODES   100000
#define N_EDGES   3200000
#define N_FEAT    128
#define N_CLASSES 16
#define K_HOPS    3
#define NUM_GRAPHS 512

// ---------------- degree / norm ----------------

__global__ void init_deg_kernel(float* __restrict__ deg) {
    int i = blockIdx.x * blockDim.x + threadIdx.x;
    if (i < N_NODES) deg[i] = 1.0f;  // self loop
}

__global__ void count_deg_kernel(const int* __restrict__ dst, float* __restrict__ deg) {
    int e = blockIdx.x * blockDim.x + threadIdx.x;
    if (e < N_EDGES) atomicAdd(&deg[dst[e]], 1.0f);
}

__global__ void finalize_dinv_kernel(float* __restrict__ deg) {
    int i = blockIdx.x * blockDim.x + threadIdx.x;
    if (i < N_NODES) deg[i] = rsqrtf(deg[i]);  // deg >= 1 always (self loop)
}

// ---------------- y = x @ W  (project features first: (S^3 x) W == S^3 (x W)) ----------------

__global__ void xw_kernel(const float* __restrict__ x, const float* __restrict__ W,
                          float* __restrict__ y) {
    __shared__ float sW[N_FEAT * N_CLASSES];   // 8 KB
    __shared__ float sx[16][N_FEAT];           // 8 KB
    int t = threadIdx.x;  // 256 threads
    for (int i = t; i < N_FEAT * N_CLASSES; i += 256) sW[i] = W[i];
    int row0 = blockIdx.x * 16;
    for (int i = t; i < 16 * N_FEAT; i += 256) {
        int r = i / N_FEAT, k = i % N_FEAT;
        int row = row0 + r;
        sx[r][k] = (row < N_NODES) ? x[(long long)row * N_FEAT + k] : 0.0f;
    }
    __syncthreads();
    int r = t >> 4, c = t & 15;
    float acc = 0.0f;
#pragma unroll 8
    for (int k = 0; k < N_FEAT; ++k) acc += sx[r][k] * sW[k * N_CLASSES + c];
    int row = row0 + r;
    if (row < N_NODES) y[row * N_CLASSES + c] = acc;
}

// ---------------- propagation hop: B = S * A  (16 features) ----------------

__global__ void self_init_kernel(const float* __restrict__ A, const float* __restrict__ dinv,
                                 float* __restrict__ B) {
    int idx = blockIdx.x * blockDim.x + threadIdx.x;
    if (idx < N_NODES * N_CLASSES) {
        int i = idx >> 4;
        float d = dinv[i];
        B[idx] = d * d * A[idx];
    }
}

__global__ void edge_scatter_kernel(const int* __restrict__ src, const int* __restrict__ dst,
                                    const float* __restrict__ dinv,
                                    const float* __restrict__ A, float* __restrict__ B) {
    long long idx = (long long)blockIdx.x * blockDim.x + threadIdx.x;
    if (idx < (long long)N_EDGES * N_CLASSES) {
        int e = (int)(idx >> 4);
        int c = (int)(idx & 15);
        int s = src[e], d = dst[e];
        float w = dinv[s] * dinv[d];
        atomicAdd(&B[d * N_CLASSES + c], w * A[s * N_CLASSES + c]);
    }
}

// ---------------- mean pooling ----------------

__global__ void pool_kernel(const float* __restrict__ y, const int* __restrict__ batch,
                            float* __restrict__ gsum, float* __restrict__ gcnt) {
    int idx = blockIdx.x * blockDim.x + threadIdx.x;
    if (idx < N_NODES * N_CLASSES) {
        int i = idx >> 4, c = idx & 15;
        int g = batch[i];
        atomicAdd(&gsum[g * N_CLASSES + c], y[idx]);
        if (c == 0) atomicAdd(&gcnt[g], 1.0f);
    }
}

// ---------------- log_softmax over [512,16] ----------------

__global__ void lsm_kernel(const float* __restrict__ gsum, const float* __restrict__ gcnt,
                           const float* __restrict__ b, float* __restrict__ out) {
    int g = blockIdx.x * blockDim.x + threadIdx.x;
    if (g < NUM_GRAPHS) {
        float cnt = fmaxf(gcnt[g], 1.0f);
        float v[N_CLASSES];
        float mx = -INFINITY;
#pragma unroll
        for (int c = 0; c < N_CLASSES; ++c) {
            v[c] = gsum[g * N_CLASSES + c] / cnt + b[c];
            mx = fmaxf(mx, v[c]);
        }
        float s = 0.0f;
#pragma unroll
        for (int c = 0; c < N_CLASSES; ++c) s += expf(v[c] - mx);
        float lse = mx + logf(s);
#pragma unroll
        for (int c = 0; c < N_CLASSES; ++c) out[g * N_CLASSES + c] = v[c] - lse;
    }
}

extern "C" void kernel_launch(void* const* d_in, const int* in_sizes, int n_in,
                              void* d_out, int out_size, void* d_ws, size_t ws_size,
                              hipStream_t stream) {
    const float* x     = (const float*)d_in[0];
    const float* W     = (const float*)d_in[1];
    const float* b     = (const float*)d_in[2];
    const int*   ei    = (const int*)d_in[3];
    const int*   batch = (const int*)d_in[4];
    float*       out   = (float*)d_out;

    const int* src = ei;             // edge_index[0]
    const int* dst = ei + N_EDGES;   // edge_index[1]

    char* ws = (char*)d_ws;
    float* dinv = (float*)ws;                                   // 400 KB
    float* yA   = (float*)(ws + 512 * 1024);                    // 6.4 MB
    float* yB   = (float*)(ws + 512 * 1024 + 8 * 1024 * 1024);  // 6.4 MB
    float* gsum = (float*)(ws + 512 * 1024 + 16 * 1024 * 1024); // 32 KB
    float* gcnt = gsum + NUM_GRAPHS * N_CLASSES;                // 2 KB

    hipMemsetAsync(gsum, 0, (NUM_GRAPHS * N_CLASSES + NUM_GRAPHS) * sizeof(float), stream);

    init_deg_kernel<<<(N_NODES + 255) / 256, 256, 0, stream>>>(dinv);
    count_deg_kernel<<<(N_EDGES + 255) / 256, 256, 0, stream>>>(dst, dinv);
    finalize_dinv_kernel<<<(N_NODES + 255) / 256, 256, 0, stream>>>(dinv);

    xw_kernel<<<(N_NODES + 15) / 16, 256, 0, stream>>>(x, W, yA);

    float* A = yA;
    float* B = yB;
    for (int h = 0; h < K_HOPS; ++h) {
        self_init_kernel<<<(N_NODES * N_CLASSES + 255) / 256, 256, 0, stream>>>(A, dinv, B);
        long long tot = (long long)N_EDGES * N_CLASSES;
        int blocks = (int)((tot + 255) / 256);
        edge_scatter_kernel<<<blocks, 256, 0, stream>>>(src, dst, dinv, A, B);
        float* tmp = A; A = B; B = tmp;
    }

    pool_kernel<<<(N_NODES * N_CLASSES + 255) / 256, 256, 0, stream>>>(A, batch, gsum, gcnt);
    lsm_kernel<<<(NUM_GRAPHS + 255) / 256, 256, 0, stream>>>(gsum, gcnt, b, out);
}

// Round 3
// 732.697 us; speedup vs baseline: 1.2863x; 1.2863x over previous
//
#include <hip/hip_runtime.h>
#include <math.h>

#define N_NODES    100000
#define N_EDGES    3200000
#define N_FEAT     128
#define N_CLASSES  16
#define K_HOPS     3
#define NUM_GRAPHS 512
#define SCAN_BLOCKS ((N_NODES + 255) / 256)   // 391

// ---------------- degree histogram (1 atomic pass) ----------------

__global__ void count_deg_kernel(const int* __restrict__ dst, int* __restrict__ deg) {
    int e = blockIdx.x * blockDim.x + threadIdx.x;
    if (e < N_EDGES) atomicAdd(&deg[dst[e]], 1);
}

// ---------------- exclusive scan of deg -> row_start ----------------

__global__ void scan1_kernel(const int* __restrict__ deg, int* __restrict__ row,
                             int* __restrict__ bsum) {
    __shared__ int tmp[256];
    int t = threadIdx.x;
    int i = blockIdx.x * 256 + t;
    int v = (i < N_NODES) ? deg[i] : 0;
    tmp[t] = v;
    __syncthreads();
    for (int off = 1; off < 256; off <<= 1) {
        int a = (t >= off) ? tmp[t - off] : 0;
        __syncthreads();
        tmp[t] += a;
        __syncthreads();
    }
    if (i < N_NODES) row[i] = tmp[t] - v;       // exclusive within block
    if (t == 255) bsum[blockIdx.x] = tmp[255];  // block total
}

__global__ void scan2_kernel(const int* __restrict__ bsum, int* __restrict__ boff) {
    __shared__ int tmp[512];
    int t = threadIdx.x;
    int v = (t < SCAN_BLOCKS) ? bsum[t] : 0;
    tmp[t] = v;
    __syncthreads();
    for (int off = 1; off < 512; off <<= 1) {
        int a = (t >= off) ? tmp[t - off] : 0;
        __syncthreads();
        tmp[t] += a;
        __syncthreads();
    }
    if (t < SCAN_BLOCKS) boff[t] = tmp[t] - v;  // exclusive block offsets
}

__global__ void scan3_kernel(int* __restrict__ row, const int* __restrict__ boff) {
    int i = blockIdx.x * 256 + threadIdx.x;
    if (i < N_NODES) row[i] += boff[blockIdx.x];
    if (i == 0) row[N_NODES] = N_EDGES;
}

// ---------------- dinv = rsqrt(deg + 1)  (self loop) ----------------

__global__ void finalize_dinv_kernel(const int* __restrict__ deg, float* __restrict__ dinv) {
    int i = blockIdx.x * blockDim.x + threadIdx.x;
    if (i < N_NODES) dinv[i] = rsqrtf((float)(deg[i] + 1));
}

__global__ void cursor_init_kernel(const int* __restrict__ row, int* __restrict__ cursor) {
    int i = blockIdx.x * blockDim.x + threadIdx.x;
    if (i < N_NODES) cursor[i] = row[i];
}

// ---------------- CSR build (1 atomic pass) ----------------

__global__ void scatter_build_kernel(const int* __restrict__ src, const int* __restrict__ dst,
                                     int* __restrict__ cursor, int* __restrict__ csr) {
    int e = blockIdx.x * blockDim.x + threadIdx.x;
    if (e < N_EDGES) {
        int d = dst[e];
        int pos = atomicAdd(&cursor[d], 1);
        csr[pos] = src[e];
    }
}

// ---------------- y = x @ W ----------------

__global__ void xw_kernel(const float* __restrict__ x, const float* __restrict__ W,
                          float* __restrict__ y) {
    __shared__ float sW[N_FEAT * N_CLASSES];   // 8 KB
    __shared__ float sx[16][N_FEAT];           // 8 KB
    int t = threadIdx.x;  // 256 threads
    for (int i = t; i < N_FEAT * N_CLASSES; i += 256) sW[i] = W[i];
    int row0 = blockIdx.x * 16;
    for (int i = t; i < 16 * N_FEAT; i += 256) {
        int r = i / N_FEAT, k = i % N_FEAT;
        int row = row0 + r;
        sx[r][k] = (row < N_NODES) ? x[(long long)row * N_FEAT + k] : 0.0f;
    }
    __syncthreads();
    int r = t >> 4, c = t & 15;
    float acc = 0.0f;
#pragma unroll 8
    for (int k = 0; k < N_FEAT; ++k) acc += sx[r][k] * sW[k * N_CLASSES + c];
    int row = row0 + r;
    if (row < N_NODES) y[row * N_CLASSES + c] = acc;
}

// ---------------- gather hop: B = S * A  (no atomics) ----------------

__global__ void hop_kernel(const int* __restrict__ row, const int* __restrict__ csr,
                           const float* __restrict__ dinv,
                           const float* __restrict__ A, float* __restrict__ B) {
    int n = blockIdx.x * 16 + (threadIdx.x >> 4);  // node (16 groups/block of 256)
    int c = threadIdx.x & 15;
    if (n >= N_NODES) return;
    int beg = row[n], end = row[n + 1];
    float acc = 0.0f;
    int j = beg;
    for (; j + 1 < end; j += 2) {
        int s0 = csr[j], s1 = csr[j + 1];
        acc += dinv[s0] * A[s0 * N_CLASSES + c] + dinv[s1] * A[s1 * N_CLASSES + c];
    }
    if (j < end) {
        int s0 = csr[j];
        acc += dinv[s0] * A[s0 * N_CLASSES + c];
    }
    float dn = dinv[n];
    B[n * N_CLASSES + c] = dn * acc + dn * dn * A[n * N_CLASSES + c];
}

// ---------------- fused pool(mean) + bias + log_softmax, atomic-free ----------------

__device__ __forceinline__ int lower_bound(const int* __restrict__ a, int n, int key) {
    int lo = 0, hi = n;
    while (lo < hi) {
        int m = (lo + hi) >> 1;
        if (a[m] < key) lo = m + 1; else hi = m;
    }
    return lo;
}

__global__ void pool_lsm_kernel(const float* __restrict__ y, const int* __restrict__ batch,
                                const float* __restrict__ b, float* __restrict__ out) {
    int g = blockIdx.x;
    int beg = lower_bound(batch, N_NODES, g);      // batch is sorted
    int end = lower_bound(batch, N_NODES, g + 1);
    int t = threadIdx.x;  // 256
    int slot = t >> 4, c = t & 15;
    float acc = 0.0f;
    for (int n = beg + slot; n < end; n += 16) acc += y[n * N_CLASSES + c];
    __shared__ float red[16][16];
    red[slot][c] = acc;
    __syncthreads();
    for (int s = 8; s >= 1; s >>= 1) {
        if (slot < s) red[slot][c] += red[slot + s][c];
        __syncthreads();
    }
    if (t < 16) {   // lanes 0..15 of wave 0
        int cnt = end - beg;
        float v = (cnt > 0) ? red[0][t] / (float)cnt + b[t] : 0.0f;
        float m = v;
        for (int mask = 1; mask < 16; mask <<= 1) m = fmaxf(m, __shfl_xor(m, mask, 64));
        float s2 = expf(v - m);
        for (int mask = 1; mask < 16; mask <<= 1) s2 += __shfl_xor(s2, mask, 64);
        out[g * N_CLASSES + t] = v - m - logf(s2);
    }
}

extern "C" void kernel_launch(void* const* d_in, const int* in_sizes, int n_in,
                              void* d_out, int out_size, void* d_ws, size_t ws_size,
                              hipStream_t stream) {
    const float* x     = (const float*)d_in[0];
    const float* W     = (const float*)d_in[1];
    const float* b     = (const float*)d_in[2];
    const int*   ei    = (const int*)d_in[3];
    const int*   batch = (const int*)d_in[4];
    float*       out   = (float*)d_out;

    const int* src = ei;             // edge_index[0]
    const int* dst = ei + N_EDGES;   // edge_index[1]

    char* ws = (char*)d_ws;
    int*   degcur = (int*)ws;                       // 400KB: deg, later cursor
    int*   row    = (int*)(ws + 0x080000);          // 400KB + 4
    float* dinv   = (float*)(ws + 0x100000);        // 400KB
    int*   bsum   = (int*)(ws + 0x180000);          // 2KB
    int*   boff   = (int*)(ws + 0x182000);          // 2KB
    int*   csr    = (int*)(ws + 0x190000);          // 12.8MB
    float* yA     = (float*)(ws + 0x190000 + 13 * 1024 * 1024);  // 6.4MB
    float* yB     = yA + (size_t)N_NODES * N_CLASSES;            // 6.4MB

    hipMemsetAsync(degcur, 0, N_NODES * sizeof(int), stream);

    count_deg_kernel<<<(N_EDGES + 255) / 256, 256, 0, stream>>>(dst, degcur);
    scan1_kernel<<<SCAN_BLOCKS, 256, 0, stream>>>(degcur, row, bsum);
    scan2_kernel<<<1, 512, 0, stream>>>(bsum, boff);
    scan3_kernel<<<SCAN_BLOCKS, 256, 0, stream>>>(row, boff);
    finalize_dinv_kernel<<<(N_NODES + 255) / 256, 256, 0, stream>>>(degcur, dinv);
    cursor_init_kernel<<<(N_NODES + 255) / 256, 256, 0, stream>>>(row, degcur);
    scatter_build_kernel<<<(N_EDGES + 255) / 256, 256, 0, stream>>>(src, dst, degcur, csr);

    xw_kernel<<<(N_NODES + 15) / 16, 256, 0, stream>>>(x, W, yA);

    hop_kernel<<<(N_NODES + 15) / 16, 256, 0, stream>>>(row, csr, dinv, yA, yB);
    hop_kernel<<<(N_NODES + 15) / 16, 256, 0, stream>>>(row, csr, dinv, yB, yA);
    hop_kernel<<<(N_NODES + 15) / 16, 256, 0, stream>>>(row, csr, dinv, yA, yB);

    pool_lsm_kernel<<<NUM_GRAPHS, 256, 0, stream>>>(yB, batch, b, out);
}

// Round 5
// 436.236 us; speedup vs baseline: 2.1605x; 1.6796x over previous
//
#include <hip/hip_runtime.h>
#include <math.h>

#define N_NODES    100000
#define N_EDGES    3200000
#define N_FEAT     128
#define N_CLASSES  16
#define NUM_GRAPHS 512
#define NB         391          // coarse bins: ceil(100000/256), bin = dst>>8
#define NBLK_A     256          // blocks in binning passes
#define EPB        12500        // edges per block: 256*12500 = 3.2M exactly
#define SCAN_BLOCKS ((N_NODES + 255) / 256)   // 391

// ---------- pass A0: per-block coarse histogram (no global atomics) ----------

__global__ void binhist_kernel(const int* __restrict__ dst, int* __restrict__ hist) {
    __shared__ int h[NB];
    int t = threadIdx.x;
    for (int i = t; i < NB; i += 256) h[i] = 0;
    __syncthreads();
    int base = blockIdx.x * EPB;
    for (int e = base + t; e < base + EPB; e += 256) atomicAdd(&h[dst[e] >> 8], 1);
    __syncthreads();
    for (int i = t; i < NB; i += 256) hist[blockIdx.x * NB + i] = h[i];  // block-major, coalesced
}

// ---------- per-bin scan over blocks -> offs[bin][block], total[bin] ----------

__global__ void offs_scan_kernel(const int* __restrict__ hist, int* __restrict__ offs,
                                 int* __restrict__ total) {
    __shared__ int v[256];
    int b = blockIdx.x, t = threadIdx.x;
    int x = hist[t * NB + b];     // strided read (L2)
    v[t] = x;
    __syncthreads();
    for (int off = 1; off < 256; off <<= 1) {
        int a = (t >= off) ? v[t - off] : 0;
        __syncthreads();
        v[t] += a;
        __syncthreads();
    }
    offs[b * 256 + t] = v[t] - x;      // exclusive over blocks (bin base added later)
    if (t == 255) total[b] = v[255];
}

// ---------- scan of bin totals -> binbase ----------

__global__ void total_scan_kernel(const int* __restrict__ total, int* __restrict__ binbase) {
    __shared__ int v[512];
    int t = threadIdx.x;
    int x = (t < NB) ? total[t] : 0;
    v[t] = x;
    __syncthreads();
    for (int off = 1; off < 512; off <<= 1) {
        int a = (t >= off) ? v[t - off] : 0;
        __syncthreads();
        v[t] += a;
        __syncthreads();
    }
    if (t < NB) binbase[t] = v[t] - x;
}

// ---------- pass A1: local counting sort by bin, coalesced scatter ----------

__global__ void binscatter_kernel(const int* __restrict__ src, const int* __restrict__ dst,
                                  const int* __restrict__ offs, const int* __restrict__ binbase,
                                  unsigned int* __restrict__ bins) {
    __shared__ int h[NB];             // hist, then cursor
    __shared__ int lstart[NB];        // local exclusive starts
    __shared__ int gstart[NB];        // global dest start for this block's run
    __shared__ int sv[512];
    __shared__ unsigned int outp[EPB];  // 50 KB
    int t = threadIdx.x, blk = blockIdx.x;
    for (int i = t; i < NB; i += 256) h[i] = 0;
    __syncthreads();
    int base = blk * EPB;
    for (int e = base + t; e < base + EPB; e += 256) atomicAdd(&h[dst[e] >> 8], 1);
    __syncthreads();
    // exclusive scan of h over 391 (padded to 512) with 256 threads
    sv[t] = (t < NB) ? h[t] : 0;
    sv[t + 256] = (t + 256 < NB) ? h[t + 256] : 0;
    __syncthreads();
    for (int off = 1; off < 512; off <<= 1) {
        int a0 = (t >= off) ? sv[t - off] : 0;
        int i1 = t + 256;
        int a1 = (i1 >= off) ? sv[i1 - off] : 0;
        __syncthreads();
        sv[t] += a0; sv[i1] += a1;
        __syncthreads();
    }
    for (int i = t; i < NB; i += 256) {
        int ls = sv[i] - h[i];
        lstart[i] = ls;
        gstart[i] = offs[i * 256 + blk] + binbase[i];
        h[i] = ls;                    // reuse as cursor
    }
    __syncthreads();
    for (int e = base + t; e < base + EPB; e += 256) {
        int s = src[e], d = dst[e];
        int b = d >> 8;
        int pos = atomicAdd(&h[b], 1);
        outp[pos] = (unsigned int)s | ((unsigned int)(d & 255) << 17);
    }
    __syncthreads();
    // coalesced copy: entries sorted by bin -> piecewise-contiguous global writes
    for (int i = t; i < EPB; i += 256) {
        int lo = 0, hi = NB - 1;                    // find bin: largest b with lstart[b] <= i
        while (lo < hi) {
            int m = (lo + hi + 1) >> 1;
            if (lstart[m] <= i) lo = m; else hi = m - 1;
        }
        bins[gstart[lo] + (i - lstart[lo])] = outp[i];
    }
}

// ---------- pass B1: per-bin node histogram -> deg (coalesced, no atomics) ----------

__global__ void bindeg_kernel(const unsigned int* __restrict__ bins,
                              const int* __restrict__ binbase, const int* __restrict__ total,
                              int* __restrict__ deg) {
    __shared__ int h[256];
    int b = blockIdx.x, t = threadIdx.x;
    h[t] = 0;
    __syncthreads();
    int base = binbase[b], cnt = total[b];
    for (int i = t; i < cnt; i += 256) atomicAdd(&h[(bins[base + i] >> 17) & 255], 1);
    __syncthreads();
    int node = b * 256 + t;
    if (node < N_NODES) deg[node] = h[t];
}

// ---------- exclusive scan of deg -> row ----------

__global__ void scan1_kernel(const int* __restrict__ deg, int* __restrict__ row,
                             int* __restrict__ bsum) {
    __shared__ int tmp[256];
    int t = threadIdx.x;
    int i = blockIdx.x * 256 + t;
    int v = (i < N_NODES) ? deg[i] : 0;
    tmp[t] = v;
    __syncthreads();
    for (int off = 1; off < 256; off <<= 1) {
        int a = (t >= off) ? tmp[t - off] : 0;
        __syncthreads();
        tmp[t] += a;
        __syncthreads();
    }
    if (i < N_NODES) row[i] = tmp[t] - v;
    if (t == 255) bsum[blockIdx.x] = tmp[255];
}

__global__ void scan2_kernel(const int* __restrict__ bsum, int* __restrict__ boff) {
    __shared__ int tmp[512];
    int t = threadIdx.x;
    int v = (t < SCAN_BLOCKS) ? bsum[t] : 0;
    tmp[t] = v;
    __syncthreads();
    for (int off = 1; off < 512; off <<= 1) {
        int a = (t >= off) ? tmp[t - off] : 0;
        __syncthreads();
        tmp[t] += a;
        __syncthreads();
    }
    if (t < SCAN_BLOCKS) boff[t] = tmp[t] - v;
}

__global__ void scan3_kernel(int* __restrict__ row, const int* __restrict__ boff) {
    int i = blockIdx.x * 256 + threadIdx.x;
    if (i < N_NODES) row[i] += boff[blockIdx.x];
    if (i == 0) row[N_NODES] = N_EDGES;
}

__global__ void finalize_dinv_kernel(const int* __restrict__ deg, float* __restrict__ dinv) {
    int i = blockIdx.x * blockDim.x + threadIdx.x;
    if (i < N_NODES) dinv[i] = rsqrtf((float)(deg[i] + 1));
}

// ---------- pass B2: per-bin counting sort by node -> exact CSR (coalesced) ----------

__global__ void binsort_kernel(const unsigned int* __restrict__ bins,
                               const int* __restrict__ binbase, const int* __restrict__ total,
                               const int* __restrict__ row, int* __restrict__ csr) {
    __shared__ int h[256], sv[256], cur[256];
    __shared__ int outs[10240];   // 40 KB; bin count ~8192 +- 90, 22 sigma margin
    int b = blockIdx.x, t = threadIdx.x;
    h[t] = 0;
    __syncthreads();
    int base = binbase[b], cnt = total[b];
    for (int i = t; i < cnt; i += 256) atomicAdd(&h[(bins[base + i] >> 17) & 255], 1);
    __syncthreads();
    sv[t] = h[t];
    __syncthreads();
    for (int off = 1; off < 256; off <<= 1) {
        int a = (t >= off) ? sv[t - off] : 0;
        __syncthreads();
        sv[t] += a;
        __syncthreads();
    }
    cur[t] = sv[t] - h[t];
    __syncthreads();
    for (int i = t; i < cnt; i += 256) {
        unsigned int p = bins[base + i];
        int pos = atomicAdd(&cur[(p >> 17) & 255], 1);
        outs[pos] = (int)(p & 0x1FFFF);
    }
    __syncthreads();
    int rb = row[b * 256];   // same address for all threads -> broadcast
    for (int i = t; i < cnt; i += 256) csr[rb + i] = outs[i];
}

// ---------- y = x @ W ----------

__global__ void xw_kernel(const float* __restrict__ x, const float* __restrict__ W,
                          float* __restrict__ y) {
    __shared__ float sW[N_FEAT * N_CLASSES];
    __shared__ float sx[16][N_FEAT];
    int t = threadIdx.x;
    for (int i = t; i < N_FEAT * N_CLASSES; i += 256) sW[i] = W[i];
    int row0 = blockIdx.x * 16;
    for (int i = t; i < 16 * N_FEAT; i += 256) {
        int r = i / N_FEAT, k = i % N_FEAT;
        int rr = row0 + r;
        sx[r][k] = (rr < N_NODES) ? x[(long long)rr * N_FEAT + k] : 0.0f;
    }
    __syncthreads();
    int r = t >> 4, c = t & 15;
    float acc = 0.0f;
#pragma unroll 8
    for (int k = 0; k < N_FEAT; ++k) acc += sx[r][k] * sW[k * N_CLASSES + c];
    int rr = row0 + r;
    if (rr < N_NODES) y[rr * N_CLASSES + c] = acc;
}

// ---------- gather hop ----------

__global__ void hop_kernel(const int* __restrict__ row, const int* __restrict__ csr,
                           const float* __restrict__ dinv,
                           const float* __restrict__ A, float* __restrict__ B) {
    int n = blockIdx.x * 16 + (threadIdx.x >> 4);
    int c = threadIdx.x & 15;
    if (n >= N_NODES) return;
    int beg = row[n], end = row[n + 1];
    float acc = 0.0f;
    int j = beg;
    for (; j + 1 < end; j += 2) {
        int s0 = csr[j], s1 = csr[j + 1];
        acc += dinv[s0] * A[s0 * N_CLASSES + c] + dinv[s1] * A[s1 * N_CLASSES + c];
    }
    if (j < end) {
        int s0 = csr[j];
        acc += dinv[s0] * A[s0 * N_CLASSES + c];
    }
    float dn = dinv[n];
    B[n * N_CLASSES + c] = dn * acc + dn * dn * A[n * N_CLASSES + c];
}

// ---------- fused pool + bias + log_softmax ----------

__device__ __forceinline__ int lower_bound(const int* __restrict__ a, int n, int key) {
    int lo = 0, hi = n;
    while (lo < hi) {
        int m = (lo + hi) >> 1;
        if (a[m] < key) lo = m + 1; else hi = m;
    }
    return lo;
}

__global__ void pool_lsm_kernel(const float* __restrict__ y, const int* __restrict__ batch,
                                const float* __restrict__ b, float* __restrict__ out) {
    int g = blockIdx.x;
    int beg = lower_bound(batch, N_NODES, g);
    int end = lower_bound(batch, N_NODES, g + 1);
    int t = threadIdx.x;
    int slot = t >> 4, c = t & 15;
    float acc = 0.0f;
    for (int n = beg + slot; n < end; n += 16) acc += y[n * N_CLASSES + c];
    __shared__ float red[16][16];
    red[slot][c] = acc;
    __syncthreads();
    for (int s = 8; s >= 1; s >>= 1) {
        if (slot < s) red[slot][c] += red[slot + s][c];
        __syncthreads();
    }
    if (t < 16) {
        int cnt = end - beg;
        float v = (cnt > 0) ? red[0][t] / (float)cnt + b[t] : 0.0f;
        float m = v;
        for (int mask = 1; mask < 16; mask <<= 1) m = fmaxf(m, __shfl_xor(m, mask, 64));
        float s2 = expf(v - m);
        for (int mask = 1; mask < 16; mask <<= 1) s2 += __shfl_xor(s2, mask, 64);
        out[g * N_CLASSES + t] = v - m - logf(s2);
    }
}

extern "C" void kernel_launch(void* const* d_in, const int* in_sizes, int n_in,
                              void* d_out, int out_size, void* d_ws, size_t ws_size,
                              hipStream_t stream) {
    const float* x     = (const float*)d_in[0];
    const float* W     = (const float*)d_in[1];
    const float* b     = (const float*)d_in[2];
    const int*   ei    = (const int*)d_in[3];
    const int*   batch = (const int*)d_in[4];
    float*       out   = (float*)d_out;

    const int* src = ei;
    const int* dst = ei + N_EDGES;

    char* ws = (char*)d_ws;
    int*   hist    = (int*)(ws + 0x000000);   // 256*391*4 = 400 KB
    int*   offs    = (int*)(ws + 0x080000);   // 391*256*4 = 400 KB
    int*   total   = (int*)(ws + 0x100000);   // 1.6 KB
    int*   binbase = (int*)(ws + 0x101000);   // 1.6 KB
    int*   bsum    = (int*)(ws + 0x102000);   // 1.6 KB
    int*   boff    = (int*)(ws + 0x103000);   // 1.6 KB
    int*   deg     = (int*)(ws + 0x110000);   // 400 KB
    int*   rowp    = (int*)(ws + 0x180000);   // 400 KB + 4
    float* dinv    = (float*)(ws + 0x200000); // 400 KB
    unsigned int* bins = (unsigned int*)(ws + 0x280000);  // 12.8 MB
    int*   csr     = (int*)(ws + 0x1000000);  // 12.8 MB
    float* yA      = (float*)(ws + 0x1D00000); // 6.4 MB
    float* yB      = (float*)(ws + 0x2400000); // 6.4 MB

    binhist_kernel<<<NBLK_A, 256, 0, stream>>>(dst, hist);
    offs_scan_kernel<<<NB, 256, 0, stream>>>(hist, offs, total);
    total_scan_kernel<<<1, 512, 0, stream>>>(total, binbase);
    binscatter_kernel<<<NBLK_A, 256, 0, stream>>>(src, dst, offs, binbase, bins);
    bindeg_kernel<<<NB, 256, 0, stream>>>(bins, binbase, total, deg);
    scan1_kernel<<<SCAN_BLOCKS, 256, 0, stream>>>(deg, rowp, bsum);
    scan2_kernel<<<1, 512, 0, stream>>>(bsum, boff);
    scan3_kernel<<<SCAN_BLOCKS, 256, 0, stream>>>(rowp, boff);
    finalize_dinv_kernel<<<(N_NODES + 255) / 256, 256, 0, stream>>>(deg, dinv);
    binsort_kernel<<<NB, 256, 0, stream>>>(bins, binbase, total, rowp, csr);

    xw_kernel<<<(N_NODES + 15) / 16, 256, 0, stream>>>(x, W, yA);

    hop_kernel<<<(N_NODES + 15) / 16, 256, 0, stream>>>(rowp, csr, dinv, yA, yB);
    hop_kernel<<<(N_NODES + 15) / 16, 256, 0, stream>>>(rowp, csr, dinv, yB, yA);
    hop_kernel<<<(N_NODES + 15) / 16, 256, 0, stream>>>(rowp, csr, dinv, yA, yB);

    pool_lsm_kernel<<<NUM_GRAPHS, 256, 0, stream>>>(yB, batch, b, out);
}